// Round 6
// baseline (834.664 us; speedup 1.0000x reference)
//
#include <hip/hip_runtime.h>
#include <math.h>

// Problem constants
#define B_    8
#define SEQ   1569      // 1 + 196*8
#define DIMX  768
#define H_    12
#define D3    192       // head dim slice (3*DH)
#define F_    8
#define NP    196
#define P1    195       // patches kept per frame
#define NCOL  2304      // 3*DIM
#define NS    6912      // fused QKV row stride (3*NCOL)
#define RSCALE (1.0f/96.0f)
#define NCHUNK 16       // cls split-K chunks
#define CH     99       // keys per chunk (16*99 >= 1569)
#define CLS_STRIDE 196  // 192 o + m + l (+pad)

typedef __bf16 bf16_t;
typedef bf16_t bf16x8 __attribute__((ext_vector_type(8)));
typedef float  f32x4  __attribute__((ext_vector_type(4)));

// async global->LDS, 16B per lane; LDS dest = wave-uniform base + lane*16
__device__ __forceinline__ void load_lds16(const bf16_t* g, bf16_t* l) {
  __builtin_amdgcn_global_load_lds(
      (const __attribute__((address_space(1))) void*)g,
      (__attribute__((address_space(3))) void*)l, 16, 0, 0);
}

// ---------------- block reduction helpers (blockDim == 256) ----------------
__device__ __forceinline__ float block_max256(float v, float* red) {
  #pragma unroll
  for (int o = 32; o > 0; o >>= 1) v = fmaxf(v, __shfl_xor(v, o, 64));
  __syncthreads();
  if ((threadIdx.x & 63) == 0) red[threadIdx.x >> 6] = v;
  __syncthreads();
  return fmaxf(fmaxf(red[0], red[1]), fmaxf(red[2], red[3]));
}

__device__ __forceinline__ float block_sum256(float v, float* red) {
  #pragma unroll
  for (int o = 32; o > 0; o >>= 1) v += __shfl_xor(v, o, 64);
  __syncthreads();
  if ((threadIdx.x & 63) == 0) red[threadIdx.x >> 6] = v;
  __syncthreads();
  return red[0] + red[1] + red[2] + red[3];
}

// ---------------- cast fp32 -> bf16 (vector of 4) ----------------
__global__ __launch_bounds__(256) void cast_f32_bf16(
    const float* __restrict__ in, bf16_t* __restrict__ out, int n4) {
  const int i = blockIdx.x * 256 + threadIdx.x;
  if (i >= n4) return;
  const float4 v = ((const float4*)in)[i];
  bf16_t o4[4] = {(bf16_t)v.x, (bf16_t)v.y, (bf16_t)v.z, (bf16_t)v.w};
  ((uint2*)out)[i] = *(uint2*)o4;
}

// ---------------- concat q/k/v biases ----------------
__global__ __launch_bounds__(256) void concat_bias_kernel(
    const float* __restrict__ bq, const float* __restrict__ bk,
    const float* __restrict__ bv, float* __restrict__ qkvb) {
  const int i = blockIdx.x * 256 + threadIdx.x;
  if (i >= NS) return;
  float v;
  if (i < NCOL) v = bq[i];
  else if (i < 2 * NCOL) v = bk[i - NCOL];
  else v = bv[i - 2 * NCOL];
  qkvb[i] = v;
}

// ---------------- transpose + cast: W (K x N fp32) -> WT (N x K bf16) -------
__global__ __launch_bounds__(256) void transpose_cast(
    const float* __restrict__ W, bf16_t* __restrict__ WT, int Kd, int Nd) {
  __shared__ float t[32][33];
  const int bn = blockIdx.x * 32;
  const int bk = blockIdx.y * 32;
  const int tx = threadIdx.x & 31, ty = threadIdx.x >> 5;  // 32 x 8
  #pragma unroll
  for (int i = 0; i < 32; i += 8)
    t[ty + i][tx] = W[(size_t)(bk + ty + i) * Nd + bn + tx];
  __syncthreads();
  #pragma unroll
  for (int i = 0; i < 32; i += 8)
    WT[(size_t)(bn + ty + i) * Kd + bk + tx] = (bf16_t)t[tx][ty + i];
}

// ---------------- bf16 MFMA GEMM: C = A @ BT^T + bias ----------------
// A: M x K bf16 packed. BT: N x K bf16 packed. bias: N fp32.
// C: M x N (fp32 or bf16). K%32==0, N%128==0, M arbitrary.
// 1D grid MT*NT with grouped-m swizzle (GROUPM m-tiles per group, n fast).
// LDS is fragment-major (16-row blocks of [kg][fr] 16B cells) so both the
// global_load_lds scatter and the ds_read_b128 fragment reads are linear
// in lane -> zero bank conflicts.
__global__ __launch_bounds__(256) void gemm_mfma_bt(
    const bf16_t* __restrict__ A, const bf16_t* __restrict__ BT,
    const float* __restrict__ bias, void* __restrict__ C,
    int M, int N, int K, int MT, int NT, int GROUPM, int outBf16) {
  __shared__ bf16_t As[128 * 32];
  __shared__ bf16_t Bs[128 * 32];
  const int tid  = threadIdx.x;
  const int wave = tid >> 6, lane = tid & 63;

  const int pid   = blockIdx.x;
  const int npg   = GROUPM * NT;
  const int group = pid / npg;
  const int first_m = group * GROUPM;
  int gsm = MT - first_m; if (gsm > GROUPM) gsm = GROUPM;
  const int lpid  = pid % npg;
  const int m_tile = first_m + lpid % gsm;
  const int n_tile = lpid / gsm;
  const int row0 = m_tile * 128, col0 = n_tile * 128;

  // staging: lane (fr, kg) fetches row fr of a 16-row block, k-seg kg
  const int fr = lane & 15, kg = lane >> 4;
  int ra0 = row0 + wave * 32 + fr;
  int ra1 = ra0 + 16;
  if (ra0 >= M) ra0 = M - 1;
  if (ra1 >= M) ra1 = M - 1;
  const bf16_t* Ap0 = A + (size_t)ra0 * K + kg * 8;
  const bf16_t* Ap1 = A + (size_t)ra1 * K + kg * 8;
  const bf16_t* Bp0 = BT + (size_t)(col0 + wave * 32 + fr) * K + kg * 8;
  const bf16_t* Bp1 = Bp0 + (size_t)16 * K;
  bf16_t* lA0 = &As[(wave * 2 + 0) * 512];
  bf16_t* lA1 = &As[(wave * 2 + 1) * 512];
  bf16_t* lB0 = &Bs[(wave * 2 + 0) * 512];
  bf16_t* lB1 = &Bs[(wave * 2 + 1) * 512];

  const int m0 = (wave & 1) * 64, n0 = (wave >> 1) * 64;
  const int mb = (wave & 1) * 4,  nb = (wave >> 1) * 4;
  f32x4 acc[4][4] = {};

  for (int k0 = 0; k0 < K; k0 += 32) {
    load_lds16(Ap0 + k0, lA0);
    load_lds16(Ap1 + k0, lA1);
    load_lds16(Bp0 + k0, lB0);
    load_lds16(Bp1 + k0, lB1);
    __syncthreads();

    bf16x8 af[4], bfr[4];
    #pragma unroll
    for (int i = 0; i < 4; ++i) {
      af[i]  = *(const bf16x8*)&As[(mb + i) * 512 + lane * 8];
      bfr[i] = *(const bf16x8*)&Bs[(nb + i) * 512 + lane * 8];
    }
    #pragma unroll
    for (int i = 0; i < 4; ++i)
      #pragma unroll
      for (int j = 0; j < 4; ++j)
        acc[i][j] = __builtin_amdgcn_mfma_f32_16x16x32_bf16(
            af[i], bfr[j], acc[i][j], 0, 0, 0);
    __syncthreads();
  }

  const int cc = lane & 15, cr4 = (lane >> 4) * 4;
  #pragma unroll
  for (int i = 0; i < 4; ++i) {
    #pragma unroll
    for (int j = 0; j < 4; ++j) {
      const int col = col0 + n0 + j * 16 + cc;
      const float bcol = bias[col];
      #pragma unroll
      for (int reg = 0; reg < 4; ++reg) {
        const int r = row0 + m0 + i * 16 + cr4 + reg;
        if (r < M) {
          const float v = acc[i][j][reg] + bcol;
          if (outBf16) ((bf16_t*)C)[(size_t)r * N + col] = (bf16_t)v;
          else         ((float*)C)[(size_t)r * N + col] = v;
        }
      }
    }
  }
}

// ---------------- xi0 scores via MFMA: S = RSCALE * Q2 @ K2^T per (b,h) ------
// grid (2, 2, 96). Q at QKV2 col 0, K at col 2*NCOL; row stride NS.
__global__ __launch_bounds__(256) void xi0_scores_mfma(
    const bf16_t* __restrict__ QKV2, float* __restrict__ Smat) {
  __shared__ bf16_t As[128 * 32];
  __shared__ bf16_t Bs[128 * 32];
  const int tid  = threadIdx.x;
  const int wave = tid >> 6, lane = tid & 63;
  const int row0 = blockIdx.x * 128, col0 = blockIdx.y * 128;
  const int bh = blockIdx.z;
  const int b = bh / H_, h = bh % H_;
  const bf16_t* Abase = QKV2 + (size_t)b * P1 * NS + h * D3;             // Q2
  const bf16_t* Bbase = QKV2 + (size_t)b * P1 * NS + 2 * NCOL + h * D3;  // K2

  const int fr = lane & 15, kg = lane >> 4;
  int ra0 = row0 + wave * 32 + fr;
  int ra1 = ra0 + 16;
  if (ra0 >= P1) ra0 = P1 - 1;
  if (ra1 >= P1) ra1 = P1 - 1;
  int cb0 = col0 + wave * 32 + fr;
  int cb1 = cb0 + 16;
  if (cb0 >= P1) cb0 = P1 - 1;
  if (cb1 >= P1) cb1 = P1 - 1;
  const bf16_t* Ap0 = Abase + (size_t)ra0 * NS + kg * 8;
  const bf16_t* Ap1 = Abase + (size_t)ra1 * NS + kg * 8;
  const bf16_t* Bp0 = Bbase + (size_t)cb0 * NS + kg * 8;
  const bf16_t* Bp1 = Bbase + (size_t)cb1 * NS + kg * 8;
  bf16_t* lA0 = &As[(wave * 2 + 0) * 512];
  bf16_t* lA1 = &As[(wave * 2 + 1) * 512];
  bf16_t* lB0 = &Bs[(wave * 2 + 0) * 512];
  bf16_t* lB1 = &Bs[(wave * 2 + 1) * 512];

  const int m0 = (wave & 1) * 64, n0 = (wave >> 1) * 64;
  const int mb = (wave & 1) * 4,  nb = (wave >> 1) * 4;
  f32x4 acc[4][4] = {};

  for (int k0 = 0; k0 < D3; k0 += 32) {
    load_lds16(Ap0 + k0, lA0);
    load_lds16(Ap1 + k0, lA1);
    load_lds16(Bp0 + k0, lB0);
    load_lds16(Bp1 + k0, lB1);
    __syncthreads();
    bf16x8 af[4], bfr[4];
    #pragma unroll
    for (int i = 0; i < 4; ++i) {
      af[i]  = *(const bf16x8*)&As[(mb + i) * 512 + lane * 8];
      bfr[i] = *(const bf16x8*)&Bs[(nb + i) * 512 + lane * 8];
    }
    #pragma unroll
    for (int i = 0; i < 4; ++i)
      #pragma unroll
      for (int j = 0; j < 4; ++j)
        acc[i][j] = __builtin_amdgcn_mfma_f32_16x16x32_bf16(
            af[i], bfr[j], acc[i][j], 0, 0, 0);
    __syncthreads();
  }

  float* S = Smat + (size_t)bh * P1 * P1;
  const int cc = lane & 15, cr4 = (lane >> 4) * 4;
  #pragma unroll
  for (int i = 0; i < 4; ++i)
    #pragma unroll
    for (int j = 0; j < 4; ++j) {
      const int col = col0 + n0 + j * 16 + cc;
      #pragma unroll
      for (int reg = 0; reg < 4; ++reg) {
        const int r = row0 + m0 + i * 16 + cr4 + reg;
        if (r < P1 && col < P1) S[(size_t)r * P1 + col] = acc[i][j][reg] * RSCALE;
      }
    }
}

// ---------------- xi0 finish: row softmax stats, colsum, PV ----------------
__global__ __launch_bounds__(256) void xi0_finish_kernel(
    const float* __restrict__ Smat, const bf16_t* __restrict__ QKV2,
    bf16_t* __restrict__ FULL9b) {
  const int bh = blockIdx.x;
  const int b = bh / H_, h = bh % H_;
  __shared__ float mrow[P1], inv_l[P1], g[P1];
  const float* S = Smat + (size_t)bh * P1 * P1;
  const int tid = threadIdx.x;

  if (tid < P1) {
    float m = -1e30f;
    for (int k = 0; k < P1; ++k) m = fmaxf(m, S[(size_t)tid * P1 + k]);
    float l = 0.f;
    for (int k = 0; k < P1; ++k)
      l += expf(S[(size_t)tid * P1 + k] - m) * ((k == 0) ? 2.f : 1.f);
    mrow[tid] = m;
    inv_l[tid] = ((tid == 0) ? 2.f : 1.f) / l;   // query-row multiplicity / denom
  }
  __syncthreads();
  if (tid < P1) {
    float s = 0.f;
    for (int r = 0; r < P1; ++r)
      s += expf(S[(size_t)r * P1 + tid] - mrow[r]) * inv_l[r];
    g[tid] = s * ((tid == 0) ? 2.f : 1.f);       // key-0 multiplicity
  }
  __syncthreads();
  if (tid < D3) {
    float acc = 0.f;
    const bf16_t* vbase = QKV2 + (size_t)b * P1 * NS + NCOL + h * D3 + tid;  // V2
    for (int k = 0; k < P1; ++k)
      acc = fmaf(g[k], (float)vbase[(size_t)k * NS], acc);
    FULL9b[((size_t)b * 9 + 1) * NCOL + h * D3 + tid] = (bf16_t)acc;
  }
}

// ---------------- cls attention, split over keys ----------------
// XQKV row layout: [q | k(Wk) | v(Wv)], stride NS.
__global__ __launch_bounds__(256) void cls_part_kernel(
    const bf16_t* __restrict__ XQKV, float* __restrict__ CLSP, int b0) {
  const int h  = blockIdx.x % H_;
  const int bl = blockIdx.x / H_;
  const int b  = b0 + bl;
  const int c  = blockIdx.y;
  const int t0 = c * CH;
  const int tend = (t0 + CH < SEQ) ? t0 + CH : SEQ;
  __shared__ float qs[D3];
  __shared__ float sc[CH];
  __shared__ float red[4];
  const int tid = threadIdx.x;

  const bf16_t* Qr = XQKV + (size_t)bl * SEQ * NS + h * D3;
  if (tid < 24) {
    const bf16x8 q8 = *(const bf16x8*)(Qr + tid * 8);
    #pragma unroll
    for (int m2 = 0; m2 < 8; ++m2) qs[tid * 8 + m2] = (float)q8[m2];
  }
  __syncthreads();

  float lmax = -1e30f;
  for (int t = t0 + tid; t < tend; t += 256) {
    const bf16_t* kr = XQKV + ((size_t)bl * SEQ + t) * NS + NCOL + h * D3;
    float acc = 0.f;
    #pragma unroll 3
    for (int d = 0; d < D3; d += 8) {
      const bf16x8 k8 = *(const bf16x8*)(kr + d);
      #pragma unroll
      for (int m2 = 0; m2 < 8; ++m2) acc = fmaf(qs[d + m2], (float)k8[m2], acc);
    }
    acc *= RSCALE;
    sc[t - t0] = acc;
    lmax = fmaxf(lmax, acc);
  }
  const float m = block_max256(lmax, red);
  float lsum = 0.f;
  for (int t = t0 + tid; t < tend; t += 256) {
    const float e = expf(sc[t - t0] - m);
    sc[t - t0] = e;
    lsum += e;
  }
  const float L = block_sum256(lsum, red);
  __syncthreads();

  float* P = CLSP + ((size_t)(b * H_ + h) * NCHUNK + c) * CLS_STRIDE;
  if (tid < D3) {
    float acc = 0.f;
    const bf16_t* vbase = XQKV + ((size_t)bl * SEQ + t0) * NS + 2 * NCOL + h * D3 + tid;
    for (int t = t0; t < tend; ++t)
      acc = fmaf(sc[t - t0], (float)vbase[(size_t)(t - t0) * NS], acc);
    P[tid] = acc;
  }
  if (tid == 192) P[192] = m;
  if (tid == 193) P[193] = L;
}

// ---------------- cls combine: merge NCHUNK partials ----------------
__global__ __launch_bounds__(256) void cls_combine_kernel(
    const float* __restrict__ CLSP, bf16_t* __restrict__ FULL9b) {
  const int bh = blockIdx.x;
  const int tid = threadIdx.x;
  const float* P = CLSP + (size_t)bh * NCHUNK * CLS_STRIDE;

  float M = -1e30f;
  #pragma unroll
  for (int c = 0; c < NCHUNK; ++c) M = fmaxf(M, P[c * CLS_STRIDE + 192]);
  float L = 0.f;
  float w[NCHUNK];
  #pragma unroll
  for (int c = 0; c < NCHUNK; ++c) {
    w[c] = expf(P[c * CLS_STRIDE + 192] - M);
    L += P[c * CLS_STRIDE + 193] * w[c];
  }
  if (tid < D3) {
    float acc = 0.f;
    #pragma unroll
    for (int c = 0; c < NCHUNK; ++c)
      acc = fmaf(w[c], P[c * CLS_STRIDE + tid], acc);
    const int b = bh / H_, h = bh % H_;
    FULL9b[((size_t)b * 9 + 0) * NCOL + h * D3 + tid] = (bf16_t)(acc / L);
  }
}

// ---------------- temporal attention per (b, h, patch) ----------------
// q col 0, k col 2*NCOL (Wv proj!), v col NCOL (Wk proj!).
__global__ __launch_bounds__(64) void temporal_kernel(
    const bf16_t* __restrict__ XQKV, bf16_t* __restrict__ T1U, int b0) {
  const int id = blockIdx.x;
  const int pi = id % P1;
  const int h  = (id / P1) % H_;
  const int bl = id / (P1 * H_);
  const int b  = b0 + bl;
  __shared__ float qs[8][196], ks[8][196];
  const int tid = threadIdx.x;  // 64

  #pragma unroll
  for (int i = 0; i < 6; ++i) {
    const int idx = tid + 64 * i;   // 0..383: [0,192) -> qs, [192,384) -> ks
    const int arr = idx / 192;
    const int c = idx % 192;        // chunk of 8 dims
    const int f = c / 24, d0 = (c % 24) * 8;
    const size_t base = ((size_t)bl * SEQ + (size_t)f * NP + pi + 2) * NS +
                        (arr ? 2 * NCOL : 0) + h * D3 + d0;
    const bf16x8 v8 = *(const bf16x8*)(XQKV + base);
    float* dst = arr ? &ks[f][d0] : &qs[f][d0];
    #pragma unroll
    for (int m2 = 0; m2 < 8; ++m2) dst[m2] = (float)v8[m2];
  }
  __syncthreads();

  const int f = tid >> 3, g = tid & 7;
  float s = 0.f;
  for (int d = 0; d < D3; d += 4) {
    const float4 a4 = *(const float4*)&qs[f][d];
    const float4 b4 = *(const float4*)&ks[g][d];
    s = fmaf(a4.x, b4.x, s); s = fmaf(a4.y, b4.y, s);
    s = fmaf(a4.z, b4.z, s); s = fmaf(a4.w, b4.w, s);
  }
  s *= RSCALE;

  float m = s;
  #pragma unroll
  for (int o = 1; o < 8; o <<= 1) m = fmaxf(m, __shfl_xor(m, o, 64));
  const float e = expf(s - m);
  float sum = e;
  #pragma unroll
  for (int o = 1; o < 8; o <<= 1) sum += __shfl_xor(sum, o, 64);
  float a = e / sum;
  #pragma unroll
  for (int o = 8; o < 64; o <<= 1) a += __shfl_xor(a, o, 64);  // column sums
  float wg[8];
  #pragma unroll
  for (int gg = 0; gg < 8; ++gg) wg[gg] = __shfl(a, gg, 64);

  const size_t vrow = (size_t)bl * SEQ * NS + NCOL + h * D3;  // values: Wk proj
  #pragma unroll
  for (int i = 0; i < 3; ++i) {
    const int d = tid + 64 * i;
    float o = 0.f;
    #pragma unroll
    for (int gg = 0; gg < 8; ++gg) {
      const bf16_t vv = XQKV[vrow + ((size_t)gg * NP + pi + 2) * NS + d];
      o = fmaf(wg[gg], (float)vv, o);
    }
    T1U[((size_t)b * P1 + pi) * NCOL + h * D3 + d] = (bf16_t)o;
  }
}

// ---------------- stage-2, xi = 1..7: 195(+dup row xi) queries over 8 keys ----
// QKV2 layout: [q2 | v2(Wk) | k2(Wv)], stride NS.
__global__ __launch_bounds__(256) void stage2_xi_kernel(
    const bf16_t* __restrict__ QKV2, bf16_t* __restrict__ FULL9b) {
  const int xi = 1 + blockIdx.x % 7;
  const int h  = (blockIdx.x / 7) % H_;
  const int b  = blockIdx.x / (7 * H_);
  __shared__ float Ks[8][196], Vs[8][196], Qs[32][196];
  __shared__ float Pp[32][8];
  const int tid = threadIdx.x;

  for (int idx = tid; idx < 192; idx += 256) {          // keys: col 2*NCOL
    const int k = idx / 24, d0 = (idx % 24) * 8;
    const bf16x8 v8 = *(const bf16x8*)(QKV2 + ((size_t)(b * P1 + xi + k)) * NS +
                                       2 * NCOL + h * D3 + d0);
    #pragma unroll
    for (int m2 = 0; m2 < 8; ++m2) Ks[k][d0 + m2] = (float)v8[m2];
  }
  for (int idx = tid; idx < 192; idx += 256) {          // values: col NCOL
    const int k = idx / 24, d0 = (idx % 24) * 8;
    const bf16x8 v8 = *(const bf16x8*)(QKV2 + ((size_t)(b * P1 + xi + k)) * NS +
                                       NCOL + h * D3 + d0);
    #pragma unroll
    for (int m2 = 0; m2 < 8; ++m2) Vs[k][d0 + m2] = (float)v8[m2];
  }

  float acc = 0.f;  // for d = tid (tid < 192)
  for (int c = 0; c < 7; ++c) {
    __syncthreads();
    for (int idx = tid; idx < 768; idx += 256) {        // 32 queries x 192 dims
      const int qr = idx / 24, d0 = (idx % 24) * 8;
      const int rq = c * 32 + qr;
      if (rq < P1) {
        const bf16x8 v8 = *(const bf16x8*)(QKV2 + ((size_t)(b * P1 + rq)) * NS +
                                           h * D3 + d0);
        #pragma unroll
        for (int m2 = 0; m2 < 8; ++m2) Qs[qr][d0 + m2] = (float)v8[m2];
      } else {
        #pragma unroll
        for (int m2 = 0; m2 < 8; ++m2) Qs[qr][d0 + m2] = 0.f;
      }
    }
    __syncthreads();
    const int grp = tid >> 3, k = tid & 7;
    float dot = 0.f;
    for (int d = 0; d < D3; d += 4) {
      const float4 a4 = *(const float4*)&Qs[grp][d];
      const float4 b4 = *(const float4*)&Ks[k][d];
      dot = fmaf(a4.x, b4.x, dot); dot = fmaf(a4.y, b4.y, dot);
      dot = fmaf(a4.z, b4.z, dot); dot = fmaf(a4.w, b4.w, dot);
    }
    dot *= RSCALE;
    float m = dot;
    #pragma unroll
    for (int o = 1; o < 8; o <<= 1) m = fmaxf(m, __shfl_xor(m, o, 64));
    const float e = expf(dot - m);
    float s = e;
    #pragma unroll
    for (int o = 1; o < 8; o <<= 1) s += __shfl_xor(s, o, 64);
    Pp[grp][k] = e / s;
    __syncthreads();
    if (tid < D3) {
      #pragma unroll 4
      for (int g2 = 0; g2 < 32; ++g2) {
        const int rq2 = c * 32 + g2;
        if (rq2 < P1) {
          const float mult = (rq2 == xi) ? 2.f : 1.f;
          float o = 0.f;
          #pragma unroll
          for (int kk = 0; kk < 8; ++kk) o = fmaf(Pp[g2][kk], Vs[kk][tid], o);
          acc = fmaf(mult, o, acc);
        }
      }
    }
  }
  if (tid < D3)
    FULL9b[((size_t)b * 9 + 1 + xi) * NCOL + h * D3 + tid] = (bf16_t)acc;
}

// ---------------- broadcast OUT9 -> full output ----------------
__global__ __launch_bounds__(256) void bcast_kernel(
    const float* __restrict__ OUT9, float* __restrict__ out) {
  const int idx = blockIdx.x * 256 + threadIdx.x;  // over float4s
  const int total = B_ * SEQ * (DIMX / 4);
  if (idx >= total) return;
  const int d4 = idx % (DIMX / 4);
  const int bs = idx / (DIMX / 4);
  const int s = bs % SEQ;
  const int b = bs / SEQ;
  const int row = (s == 0) ? 0 : 1 + ((s - 1) & 7);
  ((float4*)out)[idx] = ((const float4*)OUT9)[(size_t)(b * 9 + row) * (DIMX / 4) + d4];
}

// ---------------- launch ----------------
extern "C" void kernel_launch(void* const* d_in, const int* in_sizes, int n_in,
                              void* d_out, int out_size, void* d_ws, size_t ws_size,
                              hipStream_t stream) {
  const float* x  = (const float*)d_in[0];
  const float* Wq = (const float*)d_in[1];
  const float* bq = (const float*)d_in[2];
  const float* Wk = (const float*)d_in[3];
  const float* bk = (const float*)d_in[4];
  const float* Wv = (const float*)d_in[5];
  const float* bv = (const float*)d_in[6];
  const float* Wt = (const float*)d_in[7];
  const float* bt = (const float*)d_in[8];
  const float* Wf = (const float*)d_in[9];
  const float* bf = (const float*)d_in[10];
  float* out = (float*)d_out;
  (void)in_sizes; (void)n_in; (void)out_size;

  char* ws = (char*)d_ws;
  size_t off = 0;
  auto alloc_f32 = [&](size_t elems) {
    size_t a = (off + 63) & ~(size_t)63;
    off = a + elems * sizeof(float);
    return (float*)(ws + a);
  };
  auto alloc_bf16 = [&](size_t elems) {
    size_t a = (off + 63) & ~(size_t)63;
    off = a + elems * sizeof(bf16_t);
    return (bf16_t*)(ws + a);
  };

  bf16_t* T1Ub   = alloc_bf16((size_t)B_ * P1 * NCOL);
  bf16_t* TIUb   = alloc_bf16((size_t)B_ * P1 * DIMX);
  bf16_t* QKV2b  = alloc_bf16((size_t)B_ * P1 * NS);
  bf16_t* FULL9b = alloc_bf16((size_t)B_ * 9 * NCOL);
  float*  OUT9   = alloc_f32((size_t)B_ * 9 * DIMX);
  float*  Smat   = alloc_f32((size_t)B_ * H_ * P1 * P1);
  float*  CLSP   = alloc_f32((size_t)B_ * H_ * NCHUNK * CLS_STRIDE);
  float*  QKVbias= alloc_f32(NS);
  bf16_t* WqkvT  = alloc_bf16((size_t)3 * NCOL * DIMX);  // [WqT; WkT; WvT]
  bf16_t* WtT    = alloc_bf16((size_t)DIMX * NCOL);
  bf16_t* WfT    = alloc_bf16((size_t)DIMX * NCOL);

  // chunked stage-1 buffers
  const size_t remain = (ws_size > off) ? (ws_size - off) : 0;
  int Bc = 8;
  while (Bc > 1 &&
         (size_t)Bc * SEQ * (NS + DIMX) * sizeof(bf16_t) + 512 > remain)
    Bc >>= 1;
  bf16_t* XQKVb = alloc_bf16((size_t)Bc * SEQ * NS);
  bf16_t* xb    = alloc_bf16((size_t)Bc * SEQ * DIMX);

  // ---- weight transposes (bf16) + fused bias
  transpose_cast<<<dim3(NCOL / 32, DIMX / 32), 256, 0, stream>>>(
      Wq, WqkvT + 0 * (size_t)NCOL * DIMX, DIMX, NCOL);
  transpose_cast<<<dim3(NCOL / 32, DIMX / 32), 256, 0, stream>>>(
      Wk, WqkvT + 1 * (size_t)NCOL * DIMX, DIMX, NCOL);
  transpose_cast<<<dim3(NCOL / 32, DIMX / 32), 256, 0, stream>>>(
      Wv, WqkvT + 2 * (size_t)NCOL * DIMX, DIMX, NCOL);
  transpose_cast<<<dim3(DIMX / 32, NCOL / 32), 256, 0, stream>>>(Wt, WtT, NCOL, DIMX);
  transpose_cast<<<dim3(DIMX / 32, NCOL / 32), 256, 0, stream>>>(Wf, WfT, NCOL, DIMX);
  concat_bias_kernel<<<dim3((NS + 255) / 256), 256, 0, stream>>>(bq, bk, bv, QKVbias);

  // ---- stage 1 (chunked): cast x, fused QKV GEMM, cls + temporal attn
  for (int b0 = 0; b0 < B_; b0 += Bc) {
    const int Mrows = Bc * SEQ;
    const int n4 = Mrows * DIMX / 4;
    cast_f32_bf16<<<dim3((n4 + 255) / 256), 256, 0, stream>>>(
        x + (size_t)b0 * SEQ * DIMX, xb, n4);
    const int MT = (Mrows + 127) / 128, NT = NS / 128;
    gemm_mfma_bt<<<dim3(MT * NT), 256, 0, stream>>>(
        xb, WqkvT, QKVbias, XQKVb, Mrows, NS, DIMX, MT, NT, 8, 1);
    cls_part_kernel<<<dim3(Bc * H_, NCHUNK), 256, 0, stream>>>(XQKVb, CLSP, b0);
    temporal_kernel<<<dim3(Bc * P1 * H_), 64, 0, stream>>>(XQKVb, T1Ub, b0);
  }
  cls_combine_kernel<<<dim3(B_ * H_), 256, 0, stream>>>(CLSP, FULL9b);

  // ---- ti = merge(t1u) @ Wt + bt  (bf16 out)
  {
    const int MT = (B_ * P1 + 127) / 128, NT = DIMX / 128;
    gemm_mfma_bt<<<dim3(MT * NT), 256, 0, stream>>>(
        T1Ub, WtT, bt, TIUb, B_ * P1, DIMX, NCOL, MT, NT, 4, 1);
  }
  // ---- fused stage-2 QKV: [q2 | v2(Wk) | k2(Wv)] = ti @ Wqkv
  {
    const int MT = (B_ * P1 + 127) / 128, NT = NS / 128;
    gemm_mfma_bt<<<dim3(MT * NT), 256, 0, stream>>>(
        TIUb, WqkvT, QKVbias, QKV2b, B_ * P1, NS, DIMX, MT, NT, 4, 1);
  }

  // ---- stage-2 attentions -> FULL9 rows 1..8
  xi0_scores_mfma<<<dim3(2, 2, B_ * H_), 256, 0, stream>>>(QKV2b, Smat);
  xi0_finish_kernel<<<dim3(B_ * H_), 256, 0, stream>>>(Smat, QKV2b, FULL9b);
  stage2_xi_kernel<<<dim3(B_ * H_ * 7), 256, 0, stream>>>(QKV2b, FULL9b);

  // ---- final projection on the 9 unique rows per batch
  {
    const int MT = 1, NT = DIMX / 128;
    gemm_mfma_bt<<<dim3(MT * NT), 256, 0, stream>>>(
        FULL9b, WfT, bf, OUT9, B_ * 9, DIMX, NCOL, MT, NT, 1, 0);
  }

  // ---- broadcast to the full (B, 1569, 768) output
  {
    const int total4 = B_ * SEQ * (DIMX / 4);
    bcast_kernel<<<dim3((total4 + 255) / 256), 256, 0, stream>>>(OUT9, out);
  }
}